// Round 1
// baseline (1574.586 us; speedup 1.0000x reference)
//
#include <hip/hip_runtime.h>
#include <cstdint>
#include <cstddef>

// ---------------- constants ----------------
#define L_SEQ   2048
#define NROWS   16384            // B*L = 8*2048
#define D_MODEL 512
#define D_INNER 1024
#define D_STATE 64
#define NHEADS  16
#define CONV_DIM 1152
#define D_IN_PROJ 2192
#define D_FF 2048
#define EPS 1e-6f

typedef __bf16 bf16_t;
typedef __bf16 bf16x8 __attribute__((ext_vector_type(8)));
typedef float  f32x4  __attribute__((ext_vector_type(4)));

// workspace layout (bytes)
#define OFF_WT_IN    0ull                       // 2192*512 bf16  = 2,244,608
#define OFF_WT_OUT   2244608ull                 // 512*1024 bf16  = 1,048,576
#define OFF_W1T      3293184ull                 // 2048*512 bf16  = 2,097,152
#define OFF_W2T      5390336ull                 // 512*2048 bf16  = 2,097,152
#define OFF_U        7487488ull                 // 16384*512 bf16 = 16,777,216 (reused as h_bf16)
#define OFF_XBC_RAW  24264704ull                // 16384*1152 f32 = 75,497,472 (reused as gelu bf16)
#define OFF_XBC_CONV 99762176ull                // 16384*1152 f32 = 75,497,472
#define OFF_Y2       175259648ull               // 2*16384*1024 bf16 = 67,108,864
#define OFF_YN       242368512ull               // 16384*1024 bf16 = 33,554,432
// total ~276 MB

// ---------------- helpers ----------------
__device__ __forceinline__ void gl_lds16(const void* g, void* s) {
  __builtin_amdgcn_global_load_lds(
      (__attribute__((address_space(1))) void*)(void*)g,
      (__attribute__((address_space(3))) void*)s, 16, 0, 0);
}

__device__ __forceinline__ float block_sum256(float v, float* red) {
#pragma unroll
  for (int o = 32; o > 0; o >>= 1) v += __shfl_xor(v, o, 64);
  int w = threadIdx.x >> 6;
  if ((threadIdx.x & 63) == 0) red[w] = v;
  __syncthreads();
  return red[0] + red[1] + red[2] + red[3];
}

__device__ __forceinline__ float softplus_f(float x) {
  return (x > 20.f) ? x : log1pf(expf(x));
}
__device__ __forceinline__ float silu_f(float x) {
  return x / (1.f + expf(-x));
}
__device__ __forceinline__ float gelu_tanh_f(float x) {
  float x3 = x * x * x;
  return 0.5f * x * (1.f + tanhf(0.7978845608f * (x + 0.044715f * x3)));
}

// ---------------- weight prep: fp32 -> bf16, transposed ----------------
__global__ __launch_bounds__(256) void prep_weights_kernel(
    const float* __restrict__ W_in, const float* __restrict__ W_out,
    const float* __restrict__ W1, const float* __restrict__ W2,
    bf16_t* __restrict__ wt_in, bf16_t* __restrict__ wt_out,
    bf16_t* __restrict__ w1t, bf16_t* __restrict__ w2t) {
  const int S1 = D_IN_PROJ * 512;   // 1122304
  const int S2 = 512 * 1024;        // 524288
  const int S3 = 2048 * 512;        // 1048576
  const int S4 = 512 * 2048;        // 1048576
  const int total = S1 + S2 + S3 + S4;
  for (int i = blockIdx.x * 256 + threadIdx.x; i < total; i += gridDim.x * 256) {
    if (i < S1) {
      int n = i / 512, k = i - n * 512;
      wt_in[i] = (bf16_t)W_in[k * D_IN_PROJ + n];
    } else if (i < S1 + S2) {
      int j = i - S1; int n = j >> 10, k = j & 1023;
      wt_out[j] = (bf16_t)W_out[k * 512 + n];
    } else if (i < S1 + S2 + S3) {
      int j = i - S1 - S2; int n = j >> 9, k = j & 511;
      w1t[j] = (bf16_t)W1[k * 2048 + n];
    } else {
      int j = i - S1 - S2 - S3; int n = j >> 11, k = j & 2047;
      w2t[j] = (bf16_t)W2[k * 512 + n];
    }
  }
}

// ---------------- rmsnorm of masked input -> bf16 ----------------
__global__ __launch_bounds__(256) void rmsnorm_in_kernel(
    const float* __restrict__ x, const float* __restrict__ mask,
    bf16_t* __restrict__ u) {
  __shared__ float red[4];
  int row = blockIdx.x;
  float mk = mask[row];
  const float* xr = x + (size_t)row * 512;
  float v0 = xr[threadIdx.x] * mk;
  float v1 = xr[threadIdx.x + 256] * mk;
  float ss = block_sum256(v0 * v0 + v1 * v1, red);
  float r = rsqrtf(ss * (1.f / 512.f) + EPS);
  bf16_t* ur = u + (size_t)row * 512;
  ur[threadIdx.x] = (bf16_t)(v0 * r);
  ur[threadIdx.x + 256] = (bf16_t)(v1 * r);
}

// ---------------- rmsnorm of 2*m -> bf16 ----------------
__global__ __launch_bounds__(256) void rmsnorm2_kernel(
    const float* __restrict__ m, bf16_t* __restrict__ h) {
  __shared__ float red[4];
  int row = blockIdx.x;
  const float* mr = m + (size_t)row * 512;
  float v0 = 2.f * mr[threadIdx.x];
  float v1 = 2.f * mr[threadIdx.x + 256];
  float ss = block_sum256(v0 * v0 + v1 * v1, red);
  float r = rsqrtf(ss * (1.f / 512.f) + EPS);
  bf16_t* hr = h + (size_t)row * 512;
  hr[threadIdx.x] = (bf16_t)(v0 * r);
  hr[threadIdx.x + 256] = (bf16_t)(v1 * r);
}

// ---------------- MFMA GEMM: C[M,N] = A[M,K](bf16) @ Bt[N,K](bf16)^T ----------------
// EPI 0: o0[m*N+n] = acc                        (plain f32 store)
// EPI 1: split zxbcdt: n<1024 -> o0 (z, f32); n<2176 -> o1 (xBC raw, f32, stride 1152);
//        else -> o2 = softplus(acc + bias[n-2176]) (dt, stride 16)
// EPI 2: ob[m*N+n] = bf16(gelu(acc + bias[n]))
// EPI 3: o0[m*N+n] = acc + bias[n] + 2*extra[m*N+n]
template <int EPI>
__global__ __launch_bounds__(256, 2) void gemm_kernel(
    const bf16_t* __restrict__ A, const bf16_t* __restrict__ Bt,
    int M, int N, int K,
    float* __restrict__ o0, float* __restrict__ o1, float* __restrict__ o2,
    bf16_t* __restrict__ ob, const float* __restrict__ bias,
    const float* __restrict__ extra) {
  __shared__ bf16_t As[128 * 32];
  __shared__ bf16_t Bs[128 * 32];
  const int tid = threadIdx.x;
  const int lane = tid & 63;
  const int w = tid >> 6;
  const int tileM = blockIdx.y * 128;
  const int tileN = blockIdx.x * 128;

  f32x4 acc[4][4] = {};

  const int wm = (w >> 1) * 64;
  const int wn = (w & 1) * 64;
  const int fr = lane & 15;
  const int fk = (lane >> 4) * 8;

  for (int k0 = 0; k0 < K; k0 += 32) {
    __syncthreads();
#pragma unroll
    for (int i = 0; i < 2; ++i) {
      int rloc = w * 32 + i * 16 + (lane >> 2);
      int cb = (lane & 3) * 16;   // byte offset within 64B row
      // A tile
      const char* ga = (const char*)(A + (size_t)(tileM + rloc) * K + k0) + cb;
      gl_lds16(ga, (void*)&As[(w * 32 + i * 16) * 32]);
      // B tile (clamp row for ragged N)
      int rn = tileN + rloc;
      if (rn >= N) rn = N - 1;
      const char* gb = (const char*)(Bt + (size_t)rn * K + k0) + cb;
      gl_lds16(gb, (void*)&Bs[(w * 32 + i * 16) * 32]);
    }
    __syncthreads();

    bf16x8 av[4], bv[4];
#pragma unroll
    for (int i = 0; i < 4; ++i)
      av[i] = *(const bf16x8*)&As[(wm + i * 16 + fr) * 32 + fk];
#pragma unroll
    for (int j = 0; j < 4; ++j)
      bv[j] = *(const bf16x8*)&Bs[(wn + j * 16 + fr) * 32 + fk];
#pragma unroll
    for (int i = 0; i < 4; ++i)
#pragma unroll
      for (int j = 0; j < 4; ++j)
        acc[i][j] = __builtin_amdgcn_mfma_f32_16x16x32_bf16(av[i], bv[j], acc[i][j], 0, 0, 0);
  }

  // epilogue: C/D layout col = lane&15, row = (lane>>4)*4 + r
  const int cn = lane & 15;
  const int r0 = (lane >> 4) * 4;
#pragma unroll
  for (int i = 0; i < 4; ++i) {
#pragma unroll
    for (int j = 0; j < 4; ++j) {
      int gn = tileN + wn + j * 16 + cn;
      if (gn >= N) continue;
#pragma unroll
      for (int r = 0; r < 4; ++r) {
        int gm = tileM + wm + i * 16 + r0 + r;
        float v = acc[i][j][r];
        if (EPI == 0) {
          o0[(size_t)gm * N + gn] = v;
        } else if (EPI == 1) {
          if (gn < D_INNER) {
            o0[(size_t)gm * D_INNER + gn] = v;                       // z
          } else if (gn < D_INNER + CONV_DIM) {
            o1[(size_t)gm * CONV_DIM + (gn - D_INNER)] = v;          // xBC raw
          } else {
            int hh = gn - (D_INNER + CONV_DIM);
            o2[(size_t)gm * NHEADS + hh] = softplus_f(v + bias[hh]); // dt
          }
        } else if (EPI == 2) {
          ob[(size_t)gm * N + gn] = (bf16_t)gelu_tanh_f(v + bias[gn]);
        } else if (EPI == 3) {
          o0[(size_t)gm * N + gn] = v + bias[gn] + 2.f * extra[(size_t)gm * N + gn];
        }
      }
    }
  }
}

// ---------------- causal conv1d (k=4) + silu + mask ----------------
__global__ __launch_bounds__(384) void conv_silu_kernel(
    const float* __restrict__ xbc_raw, const float* __restrict__ conv_w,
    const float* __restrict__ conv_b, const float* __restrict__ mask,
    float* __restrict__ xbc_conv) {
  int row = blockIdx.x;
  int t = row & (L_SEQ - 1);
  float mk = mask[row];
#pragma unroll
  for (int k = 0; k < 3; ++k) {
    int c = threadIdx.x + k * 384;
    float4 wv = ((const float4*)conv_w)[c];   // conv_w[c][0..3]
    float acc = conv_b[c];
    // out[t] = sum_i w[i] * in[t-3+i]
    if (t >= 3) acc += wv.x * xbc_raw[(size_t)(row - 3) * CONV_DIM + c];
    if (t >= 2) acc += wv.y * xbc_raw[(size_t)(row - 2) * CONV_DIM + c];
    if (t >= 1) acc += wv.z * xbc_raw[(size_t)(row - 1) * CONV_DIM + c];
    acc += wv.w * xbc_raw[(size_t)row * CONV_DIM + c];
    xbc_conv[(size_t)row * CONV_DIM + c] = silu_f(acc) * mk;
  }
}

// ---------------- bidirectional selective scan ----------------
// grid = 256: bid = dir*128 + b*16 + h.  256 threads.
// thread: wave w (0..3), lane l. p = w*16 + (l&15); n-chunk = l>>4 (16 n's).
__global__ __launch_bounds__(256) void scan_kernel(
    const float* __restrict__ xbc,      // [NROWS][1152] after conv/silu/mask
    const float* __restrict__ dt_all,   // [NROWS][16] (softplus'd)
    const float* __restrict__ A_log,
    bf16_t* __restrict__ y2) {          // [2][NROWS][1024]
  int bid = blockIdx.x;
  int dir = bid >> 7;
  int b = (bid >> 4) & 7;
  int h = bid & 15;
  float A_h = -expf(A_log[h]);

  int tid = threadIdx.x;
  int w = tid >> 6, lane = tid & 63;
  int p = w * 16 + (lane & 15);
  int chunk = lane >> 4;

  __shared__ float sX[16][64];
  __shared__ float sB[16][64];
  __shared__ float sC[16][64];
  __shared__ float sDt[16];

  float hs[16] = {};
  size_t base_row = (size_t)b * L_SEQ;
  bf16_t* yout = y2 + (size_t)dir * NROWS * D_INNER;

  for (int t0 = 0; t0 < L_SEQ; t0 += 16) {
    __syncthreads();
    for (int i = tid; i < 16 * 192; i += 256) {
      int s = i / 192;
      int j = i - s * 192;
      int tt = t0 + s;
      int trow = dir ? (L_SEQ - 1 - tt) : tt;
      const float* src = xbc + (base_row + trow) * CONV_DIM;
      if (j < 64)       sX[s][j]       = src[h * 64 + j];
      else if (j < 128) sB[s][j - 64]  = src[D_INNER + (j - 64)];
      else              sC[s][j - 128] = src[D_INNER + D_STATE + (j - 128)];
    }
    if (tid < 16) {
      int tt = t0 + tid;
      int trow = dir ? (L_SEQ - 1 - tt) : tt;
      sDt[tid] = dt_all[(base_row + trow) * NHEADS + h];
    }
    __syncthreads();

#pragma unroll 4
    for (int s = 0; s < 16; ++s) {
      float dt = sDt[s];
      float dA = __expf(dt * A_h);
      float coef = dt * sX[s][p];
      const float4* Bv = (const float4*)&sB[s][chunk * 16];
      const float4* Cv = (const float4*)&sC[s][chunk * 16];
      float acc = 0.f;
#pragma unroll
      for (int q = 0; q < 4; ++q) {
        float4 bq = Bv[q];
        float4 cq = Cv[q];
        hs[q * 4 + 0] = dA * hs[q * 4 + 0] + coef * bq.x; acc += hs[q * 4 + 0] * cq.x;
        hs[q * 4 + 1] = dA * hs[q * 4 + 1] + coef * bq.y; acc += hs[q * 4 + 1] * cq.y;
        hs[q * 4 + 2] = dA * hs[q * 4 + 2] + coef * bq.z; acc += hs[q * 4 + 2] * cq.z;
        hs[q * 4 + 3] = dA * hs[q * 4 + 3] + coef * bq.w; acc += hs[q * 4 + 3] * cq.w;
      }
      acc += __shfl_xor(acc, 16, 64);
      acc += __shfl_xor(acc, 32, 64);
      if (chunk == 0) {
        int tt = t0 + s;
        int trow = dir ? (L_SEQ - 1 - tt) : tt;
        yout[(base_row + trow) * D_INNER + h * 64 + p] = (bf16_t)acc;
      }
    }
  }
}

// ---------------- combine: y = rmsnorm((yf+yb+D*xs) * silu(z)) * norm_w -> bf16 ----------------
__global__ __launch_bounds__(256) void combine_kernel(
    const bf16_t* __restrict__ y2, const float* __restrict__ xbc_conv,
    const float* __restrict__ z, const float* __restrict__ Dp,
    const float* __restrict__ norm_w, bf16_t* __restrict__ yn) {
  __shared__ float red[4];
  int row = blockIdx.x;
  const bf16_t* yf = y2 + (size_t)row * D_INNER;
  const bf16_t* yb = y2 + (size_t)NROWS * D_INNER + (size_t)row * D_INNER;
  const float* xs = xbc_conv + (size_t)row * CONV_DIM;
  const float* zr = z + (size_t)row * D_INNER;

  float g[4];
  float ss = 0.f;
#pragma unroll
  for (int k = 0; k < 4; ++k) {
    int c = threadIdx.x + k * 256;
    float v = (float)yf[c] + (float)yb[c] + Dp[c >> 6] * xs[c];
    float gg = v * silu_f(zr[c]);
    g[k] = gg;
    ss += gg * gg;
  }
  ss = block_sum256(ss, red);
  float r = rsqrtf(ss * (1.f / 1024.f) + EPS);
  bf16_t* yr = yn + (size_t)row * D_INNER;
#pragma unroll
  for (int k = 0; k < 4; ++k) {
    int c = threadIdx.x + k * 256;
    yr[c] = (bf16_t)(g[k] * r * norm_w[c]);
  }
}

// ---------------- launcher ----------------
extern "C" void kernel_launch(void* const* d_in, const int* in_sizes, int n_in,
                              void* d_out, int out_size, void* d_ws, size_t ws_size,
                              hipStream_t stream) {
  const float* x       = (const float*)d_in[0];
  const float* mask    = (const float*)d_in[1];
  const float* W_in    = (const float*)d_in[2];
  const float* conv_w  = (const float*)d_in[3];
  const float* conv_b  = (const float*)d_in[4];
  const float* dt_bias = (const float*)d_in[5];
  const float* A_log   = (const float*)d_in[6];
  const float* Dp      = (const float*)d_in[7];
  const float* norm_w  = (const float*)d_in[8];
  const float* W_out   = (const float*)d_in[9];
  const float* W1      = (const float*)d_in[10];
  const float* b1      = (const float*)d_in[11];
  const float* W2      = (const float*)d_in[12];
  const float* b2      = (const float*)d_in[13];

  float* out_x  = (float*)d_out;                       // 16384*512
  float* out_m  = out_x + (size_t)NROWS * 512;         // 16384*512
  float* out_dt = out_m + (size_t)NROWS * 512;         // 16384*16
  float* out_z  = out_dt + (size_t)NROWS * NHEADS;     // 16384*1024

  char* ws = (char*)d_ws;
  bf16_t* wt_in    = (bf16_t*)(ws + OFF_WT_IN);
  bf16_t* wt_out   = (bf16_t*)(ws + OFF_WT_OUT);
  bf16_t* w1t      = (bf16_t*)(ws + OFF_W1T);
  bf16_t* w2t      = (bf16_t*)(ws + OFF_W2T);
  bf16_t* u_bf     = (bf16_t*)(ws + OFF_U);            // later reused as h_bf
  float*  xbc_raw  = (float*)(ws + OFF_XBC_RAW);       // later reused as gelu bf16
  float*  xbc_conv = (float*)(ws + OFF_XBC_CONV);
  bf16_t* y2       = (bf16_t*)(ws + OFF_Y2);
  bf16_t* yn       = (bf16_t*)(ws + OFF_YN);
  bf16_t* h_bf     = u_bf;
  bf16_t* gelu_bf  = (bf16_t*)(ws + OFF_XBC_RAW);

  // 1. weights -> bf16 transposed
  prep_weights_kernel<<<14624, 256, 0, stream>>>(W_in, W_out, W1, W2, wt_in, wt_out, w1t, w2t);
  // 2. u = rmsnorm(x*mask)
  rmsnorm_in_kernel<<<NROWS, 256, 0, stream>>>(x, mask, u_bf);
  // 3. zxbcdt = u @ W_in, split into z / xBC / dt(softplus)
  gemm_kernel<1><<<dim3(18, 128), 256, 0, stream>>>(u_bf, wt_in, NROWS, D_IN_PROJ, 512,
                                                    out_z, xbc_raw, out_dt, nullptr, dt_bias, nullptr);
  // 4. conv1d + silu + mask
  conv_silu_kernel<<<NROWS, 384, 0, stream>>>(xbc_raw, conv_w, conv_b, mask, xbc_conv);
  // 5. bidirectional scan
  scan_kernel<<<256, 256, 0, stream>>>(xbc_conv, out_dt, A_log, y2);
  // 6. combine + gated rmsnorm
  combine_kernel<<<NROWS, 256, 0, stream>>>(y2, xbc_conv, out_z, Dp, norm_w, yn);
  // 7. m = yn @ W_out
  gemm_kernel<0><<<dim3(4, 128), 256, 0, stream>>>(yn, wt_out, NROWS, 512, 1024,
                                                   out_m, nullptr, nullptr, nullptr, nullptr, nullptr);
  // 8. h = rmsnorm(2m)
  rmsnorm2_kernel<<<NROWS, 256, 0, stream>>>(out_m, h_bf);
  // 9. g = gelu(h @ W1 + b1)
  gemm_kernel<2><<<dim3(16, 128), 256, 0, stream>>>(h_bf, w1t, NROWS, D_FF, 512,
                                                    nullptr, nullptr, nullptr, gelu_bf, b1, nullptr);
  // 10. x = 2m + g @ W2 + b2
  gemm_kernel<3><<<dim3(4, 128), 256, 0, stream>>>(gelu_bf, w2t, NROWS, 512, D_FF,
                                                   out_x, nullptr, nullptr, nullptr, b2, out_m);
}

// Round 2
// 1206.889 us; speedup vs baseline: 1.3047x; 1.3047x over previous
//
#include <hip/hip_runtime.h>
#include <cstdint>
#include <cstddef>

// ---------------- constants ----------------
#define L_SEQ   2048
#define NROWS   16384            // B*L = 8*2048
#define D_MODEL 512
#define D_INNER 1024
#define D_STATE 64
#define NHEADS  16
#define CONV_DIM 1152
#define D_IN_PROJ 2192
#define D_FF 2048
#define EPS 1e-6f

typedef __bf16 bf16_t;
typedef __bf16 bf16x8 __attribute__((ext_vector_type(8)));
typedef float  f32x4  __attribute__((ext_vector_type(4)));

// workspace layout (bytes)
#define OFF_WT_IN    0ull                       // 2192*512 bf16  = 2,244,608
#define OFF_WT_OUT   2244608ull                 // 512*1024 bf16  = 1,048,576
#define OFF_W1T      3293184ull                 // 2048*512 bf16  = 2,097,152
#define OFF_W2T      5390336ull                 // 512*2048 bf16  = 2,097,152
#define OFF_U        7487488ull                 // 16384*512 bf16 = 16,777,216 (reused as h_bf16)
#define OFF_XBC_RAW  24264704ull                // 16384*1152 f32 = 75,497,472 (reused as gelu bf16)
#define OFF_XBC_CONV 99762176ull                // 16384*1152 f32 = 75,497,472
#define OFF_Y2       175259648ull               // 2*16384*1024 bf16 = 67,108,864
#define OFF_YN       242368512ull               // 16384*1024 bf16 = 33,554,432
// total ~276 MB

// ---------------- helpers ----------------
__device__ __forceinline__ void gl_lds16(const void* g, void* s) {
  __builtin_amdgcn_global_load_lds(
      (__attribute__((address_space(1))) void*)(void*)g,
      (__attribute__((address_space(3))) void*)s, 16, 0, 0);
}

__device__ __forceinline__ float block_sum256(float v, float* red) {
#pragma unroll
  for (int o = 32; o > 0; o >>= 1) v += __shfl_xor(v, o, 64);
  int w = threadIdx.x >> 6;
  if ((threadIdx.x & 63) == 0) red[w] = v;
  __syncthreads();
  return red[0] + red[1] + red[2] + red[3];
}

__device__ __forceinline__ float softplus_f(float x) {
  return (x > 20.f) ? x : log1pf(expf(x));
}
__device__ __forceinline__ float silu_f(float x) {
  return x / (1.f + expf(-x));
}
__device__ __forceinline__ float gelu_tanh_f(float x) {
  float x3 = x * x * x;
  return 0.5f * x * (1.f + tanhf(0.7978845608f * (x + 0.044715f * x3)));
}

// ---------------- weight prep: fp32 -> bf16, transposed ----------------
__global__ __launch_bounds__(256) void prep_weights_kernel(
    const float* __restrict__ W_in, const float* __restrict__ W_out,
    const float* __restrict__ W1, const float* __restrict__ W2,
    bf16_t* __restrict__ wt_in, bf16_t* __restrict__ wt_out,
    bf16_t* __restrict__ w1t, bf16_t* __restrict__ w2t) {
  const int S1 = D_IN_PROJ * 512;   // 1122304
  const int S2 = 512 * 1024;        // 524288
  const int S3 = 2048 * 512;        // 1048576
  const int S4 = 512 * 2048;        // 1048576
  const int total = S1 + S2 + S3 + S4;
  for (int i = blockIdx.x * 256 + threadIdx.x; i < total; i += gridDim.x * 256) {
    if (i < S1) {
      int n = i / 512, k = i - n * 512;
      wt_in[i] = (bf16_t)W_in[k * D_IN_PROJ + n];
    } else if (i < S1 + S2) {
      int j = i - S1; int n = j >> 10, k = j & 1023;
      wt_out[j] = (bf16_t)W_out[k * 512 + n];
    } else if (i < S1 + S2 + S3) {
      int j = i - S1 - S2; int n = j >> 9, k = j & 511;
      w1t[j] = (bf16_t)W1[k * 2048 + n];
    } else {
      int j = i - S1 - S2 - S3; int n = j >> 11, k = j & 2047;
      w2t[j] = (bf16_t)W2[k * 512 + n];
    }
  }
}

// ---------------- rmsnorm of masked input -> bf16 ----------------
__global__ __launch_bounds__(256) void rmsnorm_in_kernel(
    const float* __restrict__ x, const float* __restrict__ mask,
    bf16_t* __restrict__ u) {
  __shared__ float red[4];
  int row = blockIdx.x;
  float mk = mask[row];
  const float* xr = x + (size_t)row * 512;
  float v0 = xr[threadIdx.x] * mk;
  float v1 = xr[threadIdx.x + 256] * mk;
  float ss = block_sum256(v0 * v0 + v1 * v1, red);
  float r = rsqrtf(ss * (1.f / 512.f) + EPS);
  bf16_t* ur = u + (size_t)row * 512;
  ur[threadIdx.x] = (bf16_t)(v0 * r);
  ur[threadIdx.x + 256] = (bf16_t)(v1 * r);
}

// ---------------- rmsnorm of 2*m -> bf16 ----------------
__global__ __launch_bounds__(256) void rmsnorm2_kernel(
    const float* __restrict__ m, bf16_t* __restrict__ h) {
  __shared__ float red[4];
  int row = blockIdx.x;
  const float* mr = m + (size_t)row * 512;
  float v0 = 2.f * mr[threadIdx.x];
  float v1 = 2.f * mr[threadIdx.x + 256];
  float ss = block_sum256(v0 * v0 + v1 * v1, red);
  float r = rsqrtf(ss * (1.f / 512.f) + EPS);
  bf16_t* hr = h + (size_t)row * 512;
  hr[threadIdx.x] = (bf16_t)(v0 * r);
  hr[threadIdx.x + 256] = (bf16_t)(v1 * r);
}

// ---------------- MFMA GEMM: C[M,N] = A[M,K](bf16) @ Bt[N,K](bf16)^T ----------------
template <int EPI>
__global__ __launch_bounds__(256, 2) void gemm_kernel(
    const bf16_t* __restrict__ A, const bf16_t* __restrict__ Bt,
    int M, int N, int K,
    float* __restrict__ o0, float* __restrict__ o1, float* __restrict__ o2,
    bf16_t* __restrict__ ob, const float* __restrict__ bias,
    const float* __restrict__ extra) {
  __shared__ bf16_t As[128 * 32];
  __shared__ bf16_t Bs[128 * 32];
  const int tid = threadIdx.x;
  const int lane = tid & 63;
  const int w = tid >> 6;
  const int tileM = blockIdx.y * 128;
  const int tileN = blockIdx.x * 128;

  f32x4 acc[4][4] = {};

  const int wm = (w >> 1) * 64;
  const int wn = (w & 1) * 64;
  const int fr = lane & 15;
  const int fk = (lane >> 4) * 8;

  for (int k0 = 0; k0 < K; k0 += 32) {
    __syncthreads();
#pragma unroll
    for (int i = 0; i < 2; ++i) {
      int rloc = w * 32 + i * 16 + (lane >> 2);
      int cb = (lane & 3) * 16;   // byte offset within 64B row
      const char* ga = (const char*)(A + (size_t)(tileM + rloc) * K + k0) + cb;
      gl_lds16(ga, (void*)&As[(w * 32 + i * 16) * 32]);
      int rn = tileN + rloc;
      if (rn >= N) rn = N - 1;
      const char* gb = (const char*)(Bt + (size_t)rn * K + k0) + cb;
      gl_lds16(gb, (void*)&Bs[(w * 32 + i * 16) * 32]);
    }
    __syncthreads();

    bf16x8 av[4], bv[4];
#pragma unroll
    for (int i = 0; i < 4; ++i)
      av[i] = *(const bf16x8*)&As[(wm + i * 16 + fr) * 32 + fk];
#pragma unroll
    for (int j = 0; j < 4; ++j)
      bv[j] = *(const bf16x8*)&Bs[(wn + j * 16 + fr) * 32 + fk];
#pragma unroll
    for (int i = 0; i < 4; ++i)
#pragma unroll
      for (int j = 0; j < 4; ++j)
        acc[i][j] = __builtin_amdgcn_mfma_f32_16x16x32_bf16(av[i], bv[j], acc[i][j], 0, 0, 0);
  }

  const int cn = lane & 15;
  const int r0 = (lane >> 4) * 4;
#pragma unroll
  for (int i = 0; i < 4; ++i) {
#pragma unroll
    for (int j = 0; j < 4; ++j) {
      int gn = tileN + wn + j * 16 + cn;
      if (gn >= N) continue;
#pragma unroll
      for (int r = 0; r < 4; ++r) {
        int gm = tileM + wm + i * 16 + r0 + r;
        float v = acc[i][j][r];
        if (EPI == 0) {
          o0[(size_t)gm * N + gn] = v;
        } else if (EPI == 1) {
          if (gn < D_INNER) {
            o0[(size_t)gm * D_INNER + gn] = v;                       // z
          } else if (gn < D_INNER + CONV_DIM) {
            o1[(size_t)gm * CONV_DIM + (gn - D_INNER)] = v;          // xBC raw
          } else {
            int hh = gn - (D_INNER + CONV_DIM);
            o2[(size_t)gm * NHEADS + hh] = softplus_f(v + bias[hh]); // dt
          }
        } else if (EPI == 2) {
          ob[(size_t)gm * N + gn] = (bf16_t)gelu_tanh_f(v + bias[gn]);
        } else if (EPI == 3) {
          o0[(size_t)gm * N + gn] = v + bias[gn] + 2.f * extra[(size_t)gm * N + gn];
        }
      }
    }
  }
}

// ---------------- causal conv1d (k=4) + silu + mask ----------------
__global__ __launch_bounds__(384) void conv_silu_kernel(
    const float* __restrict__ xbc_raw, const float* __restrict__ conv_w,
    const float* __restrict__ conv_b, const float* __restrict__ mask,
    float* __restrict__ xbc_conv) {
  int row = blockIdx.x;
  int t = row & (L_SEQ - 1);
  float mk = mask[row];
#pragma unroll
  for (int k = 0; k < 3; ++k) {
    int c = threadIdx.x + k * 384;
    float4 wv = ((const float4*)conv_w)[c];   // conv_w[c][0..3]
    float acc = conv_b[c];
    if (t >= 3) acc += wv.x * xbc_raw[(size_t)(row - 3) * CONV_DIM + c];
    if (t >= 2) acc += wv.y * xbc_raw[(size_t)(row - 2) * CONV_DIM + c];
    if (t >= 1) acc += wv.z * xbc_raw[(size_t)(row - 1) * CONV_DIM + c];
    acc += wv.w * xbc_raw[(size_t)row * CONV_DIM + c];
    xbc_conv[(size_t)row * CONV_DIM + c] = silu_f(acc) * mk;
  }
}

// ---------------- bidirectional selective scan (p-split 4-way) ----------------
// grid = 1024: bid = dir*512 + b*64 + h*4 + psplit. 256 threads.
// Block handles 16 p's (p = psplit*16 + w*4 + (lane>>4)), all 64 n's
// (n0 = (lane&15)*4, 4 states/thread). y-reduction over n is 4 xor-shuffles
// within the wave (lanes differing in bits 0..3 share the same p).
__global__ __launch_bounds__(256) void scan_kernel(
    const float* __restrict__ xbc,      // [NROWS][1152] after conv/silu/mask
    const float* __restrict__ dt_all,   // [NROWS][16] (softplus'd)
    const float* __restrict__ A_log,
    bf16_t* __restrict__ y2) {          // [2][NROWS][1024]
  int bid = blockIdx.x;
  int psplit = bid & 3;
  int h = (bid >> 2) & 15;
  int b = (bid >> 6) & 7;
  int dir = bid >> 9;
  float A_h = -expf(A_log[h]);

  int tid = threadIdx.x;
  int w = tid >> 6, lane = tid & 63;
  int p_local = w * 4 + (lane >> 4);       // 0..15
  int p = psplit * 16 + p_local;           // 0..63 within head
  int n0 = (lane & 15) * 4;                // this thread's 4 states

  __shared__ float sB[16][64];
  __shared__ float sC[16][64];
  __shared__ float sX[16][16];
  __shared__ float sDt[16];

  float hs[4] = {};
  size_t base_row = (size_t)b * L_SEQ;
  bf16_t* yout = y2 + (size_t)dir * NROWS * D_INNER;

  for (int t0 = 0; t0 < L_SEQ; t0 += 16) {
    __syncthreads();
    // stage B and C: 16 steps x 64 floats each
    {
      int s = tid >> 6;          // wave w stages steps {w, w+4, w+8, w+12}
      int j = tid & 63;
#pragma unroll
      for (int ss = 0; ss < 4; ++ss) {
        int st = s + ss * 4;
        int tt = t0 + st;
        int trow = dir ? (L_SEQ - 1 - tt) : tt;
        const float* src = xbc + (base_row + trow) * CONV_DIM + D_INNER;
        sB[st][j] = src[j];
        sC[st][j] = src[D_STATE + j];
      }
    }
    // stage X slice (16 steps x 16 p) and dt
    {
      int s = tid >> 4;
      if (s < 16) {
        int pl = tid & 15;
        int tt = t0 + s;
        int trow = dir ? (L_SEQ - 1 - tt) : tt;
        sX[s][pl] = xbc[(base_row + trow) * CONV_DIM + h * 64 + psplit * 16 + pl];
        if (pl == 0) sDt[s] = dt_all[(base_row + trow) * NHEADS + h];
      }
    }
    __syncthreads();

    // hoist exp + X reads out of the serial chain
    float dA[16], coef[16];
#pragma unroll
    for (int s = 0; s < 16; ++s) {
      float dt = sDt[s];
      dA[s] = __expf(dt * A_h);
      coef[s] = dt * sX[s][p_local];
    }

#pragma unroll
    for (int s = 0; s < 16; ++s) {
      float4 bq = *(const float4*)&sB[s][n0];
      float4 cq = *(const float4*)&sC[s][n0];
      float a0, a1;
      hs[0] = dA[s] * hs[0] + coef[s] * bq.x;
      hs[1] = dA[s] * hs[1] + coef[s] * bq.y;
      hs[2] = dA[s] * hs[2] + coef[s] * bq.z;
      hs[3] = dA[s] * hs[3] + coef[s] * bq.w;
      a0 = hs[0] * cq.x + hs[1] * cq.y;
      a1 = hs[2] * cq.z + hs[3] * cq.w;
      float acc = a0 + a1;
      acc += __shfl_xor(acc, 1, 64);
      acc += __shfl_xor(acc, 2, 64);
      acc += __shfl_xor(acc, 4, 64);
      acc += __shfl_xor(acc, 8, 64);
      if ((lane & 15) == 0) {
        int tt = t0 + s;
        int trow = dir ? (L_SEQ - 1 - tt) : tt;
        yout[(base_row + trow) * D_INNER + h * 64 + p] = (bf16_t)acc;
      }
    }
  }
}

// ---------------- combine: y = rmsnorm((yf+yb+D*xs) * silu(z)) * norm_w -> bf16 ----------------
__global__ __launch_bounds__(256) void combine_kernel(
    const bf16_t* __restrict__ y2, const float* __restrict__ xbc_conv,
    const float* __restrict__ z, const float* __restrict__ Dp,
    const float* __restrict__ norm_w, bf16_t* __restrict__ yn) {
  __shared__ float red[4];
  int row = blockIdx.x;
  const bf16_t* yf = y2 + (size_t)row * D_INNER;
  const bf16_t* yb = y2 + (size_t)NROWS * D_INNER + (size_t)row * D_INNER;
  const float* xs = xbc_conv + (size_t)row * CONV_DIM;
  const float* zr = z + (size_t)row * D_INNER;

  float g[4];
  float ss = 0.f;
#pragma unroll
  for (int k = 0; k < 4; ++k) {
    int c = threadIdx.x + k * 256;
    float v = (float)yf[c] + (float)yb[c] + Dp[c >> 6] * xs[c];
    float gg = v * silu_f(zr[c]);
    g[k] = gg;
    ss += gg * gg;
  }
  ss = block_sum256(ss, red);
  float r = rsqrtf(ss * (1.f / 1024.f) + EPS);
  bf16_t* yr = yn + (size_t)row * D_INNER;
#pragma unroll
  for (int k = 0; k < 4; ++k) {
    int c = threadIdx.x + k * 256;
    yr[c] = (bf16_t)(g[k] * r * norm_w[c]);
  }
}

// ---------------- launcher ----------------
extern "C" void kernel_launch(void* const* d_in, const int* in_sizes, int n_in,
                              void* d_out, int out_size, void* d_ws, size_t ws_size,
                              hipStream_t stream) {
  const float* x       = (const float*)d_in[0];
  const float* mask    = (const float*)d_in[1];
  const float* W_in    = (const float*)d_in[2];
  const float* conv_w  = (const float*)d_in[3];
  const float* conv_b  = (const float*)d_in[4];
  const float* dt_bias = (const float*)d_in[5];
  const float* A_log   = (const float*)d_in[6];
  const float* Dp      = (const float*)d_in[7];
  const float* norm_w  = (const float*)d_in[8];
  const float* W_out   = (const float*)d_in[9];
  const float* W1      = (const float*)d_in[10];
  const float* b1      = (const float*)d_in[11];
  const float* W2      = (const float*)d_in[12];
  const float* b2      = (const float*)d_in[13];

  float* out_x  = (float*)d_out;                       // 16384*512
  float* out_m  = out_x + (size_t)NROWS * 512;         // 16384*512
  float* out_dt = out_m + (size_t)NROWS * 512;         // 16384*16
  float* out_z  = out_dt + (size_t)NROWS * NHEADS;     // 16384*1024

  char* ws = (char*)d_ws;
  bf16_t* wt_in    = (bf16_t*)(ws + OFF_WT_IN);
  bf16_t* wt_out   = (bf16_t*)(ws + OFF_WT_OUT);
  bf16_t* w1t      = (bf16_t*)(ws + OFF_W1T);
  bf16_t* w2t      = (bf16_t*)(ws + OFF_W2T);
  bf16_t* u_bf     = (bf16_t*)(ws + OFF_U);            // later reused as h_bf
  float*  xbc_raw  = (float*)(ws + OFF_XBC_RAW);       // later reused as gelu bf16
  float*  xbc_conv = (float*)(ws + OFF_XBC_CONV);
  bf16_t* y2       = (bf16_t*)(ws + OFF_Y2);
  bf16_t* yn       = (bf16_t*)(ws + OFF_YN);
  bf16_t* h_bf     = u_bf;
  bf16_t* gelu_bf  = (bf16_t*)(ws + OFF_XBC_RAW);

  // 1. weights -> bf16 transposed
  prep_weights_kernel<<<14624, 256, 0, stream>>>(W_in, W_out, W1, W2, wt_in, wt_out, w1t, w2t);
  // 2. u = rmsnorm(x*mask)
  rmsnorm_in_kernel<<<NROWS, 256, 0, stream>>>(x, mask, u_bf);
  // 3. zxbcdt = u @ W_in, split into z / xBC / dt(softplus)
  gemm_kernel<1><<<dim3(18, 128), 256, 0, stream>>>(u_bf, wt_in, NROWS, D_IN_PROJ, 512,
                                                    out_z, xbc_raw, out_dt, nullptr, dt_bias, nullptr);
  // 4. conv1d + silu + mask
  conv_silu_kernel<<<NROWS, 384, 0, stream>>>(xbc_raw, conv_w, conv_b, mask, xbc_conv);
  // 5. bidirectional scan (p-split 4-way: 4 blocks/CU for latency hiding)
  scan_kernel<<<1024, 256, 0, stream>>>(xbc_conv, out_dt, A_log, y2);
  // 6. combine + gated rmsnorm
  combine_kernel<<<NROWS, 256, 0, stream>>>(y2, xbc_conv, out_z, Dp, norm_w, yn);
  // 7. m = yn @ W_out
  gemm_kernel<0><<<dim3(4, 128), 256, 0, stream>>>(yn, wt_out, NROWS, 512, 1024,
                                                   out_m, nullptr, nullptr, nullptr, nullptr, nullptr);
  // 8. h = rmsnorm(2m)
  rmsnorm2_kernel<<<NROWS, 256, 0, stream>>>(out_m, h_bf);
  // 9. g = gelu(h @ W1 + b1)
  gemm_kernel<2><<<dim3(16, 128), 256, 0, stream>>>(h_bf, w1t, NROWS, D_FF, 512,
                                                    nullptr, nullptr, nullptr, gelu_bf, b1, nullptr);
  // 10. x = 2m + g @ W2 + b2
  gemm_kernel<3><<<dim3(4, 128), 256, 0, stream>>>(gelu_bf, w2t, NROWS, 512, D_FF,
                                                   out_x, nullptr, nullptr, nullptr, b2, out_m);
}

// Round 3
// 810.377 us; speedup vs baseline: 1.9430x; 1.4893x over previous
//
#include <hip/hip_runtime.h>
#include <cstdint>
#include <cstddef>

// ---------------- constants ----------------
#define L_SEQ   2048
#define NROWS   16384            // B*L = 8*2048
#define D_MODEL 512
#define D_INNER 1024
#define D_STATE 64
#define NHEADS  16
#define CONV_DIM 1152
#define D_IN_PROJ 2192
#define D_FF 2048
#define EPS 1e-6f

typedef __bf16 bf16_t;
typedef __bf16 bf16x8 __attribute__((ext_vector_type(8)));
typedef float  f32x4  __attribute__((ext_vector_type(4)));

// workspace layout (bytes)
#define OFF_WT_IN    0ull                       // 2192*512 bf16  = 2,244,608
#define OFF_WT_OUT   2244608ull                 // 512*1024 bf16  = 1,048,576
#define OFF_W1T      3293184ull                 // 2048*512 bf16  = 2,097,152
#define OFF_W2T      5390336ull                 // 512*2048 bf16  = 2,097,152
#define OFF_U        7487488ull                 // 16384*512 bf16 (u_bf; reused: la_buf during scan, h_bf later)
#define OFF_XBC_RAW  24264704ull                // 16384*1152 f32 (xbc_raw; reused: Tc_buf during scan, gelu bf16 later)
#define OFF_XBC_CONV 99762176ull                // 16384*1152 f32
#define OFF_Y2       175259648ull               // 2*16384*1024 bf16 = 67,108,864
#define OFF_YN       242368512ull               // 16384*1024 bf16 = 33,554,432
// total ~276 MB

// ---------------- helpers ----------------
__device__ __forceinline__ void gl_lds16(const void* g, void* s) {
  __builtin_amdgcn_global_load_lds(
      (__attribute__((address_space(1))) void*)(void*)g,
      (__attribute__((address_space(3))) void*)s, 16, 0, 0);
}

__device__ __forceinline__ float block_sum256(float v, float* red) {
#pragma unroll
  for (int o = 32; o > 0; o >>= 1) v += __shfl_xor(v, o, 64);
  int w = threadIdx.x >> 6;
  if ((threadIdx.x & 63) == 0) red[w] = v;
  __syncthreads();
  return red[0] + red[1] + red[2] + red[3];
}

__device__ __forceinline__ float softplus_f(float x) {
  return (x > 20.f) ? x : log1pf(expf(x));
}
__device__ __forceinline__ float silu_f(float x) {
  return x / (1.f + expf(-x));
}
__device__ __forceinline__ float gelu_tanh_f(float x) {
  float x3 = x * x * x;
  return 0.5f * x * (1.f + tanhf(0.7978845608f * (x + 0.044715f * x3)));
}

// ---------------- weight prep: fp32 -> bf16, transposed ----------------
__global__ __launch_bounds__(256) void prep_weights_kernel(
    const float* __restrict__ W_in, const float* __restrict__ W_out,
    const float* __restrict__ W1, const float* __restrict__ W2,
    bf16_t* __restrict__ wt_in, bf16_t* __restrict__ wt_out,
    bf16_t* __restrict__ w1t, bf16_t* __restrict__ w2t) {
  const int S1 = D_IN_PROJ * 512;   // 1122304
  const int S2 = 512 * 1024;        // 524288
  const int S3 = 2048 * 512;        // 1048576
  const int S4 = 512 * 2048;        // 1048576
  const int total = S1 + S2 + S3 + S4;
  for (int i = blockIdx.x * 256 + threadIdx.x; i < total; i += gridDim.x * 256) {
    if (i < S1) {
      int n = i / 512, k = i - n * 512;
      wt_in[i] = (bf16_t)W_in[k * D_IN_PROJ + n];
    } else if (i < S1 + S2) {
      int j = i - S1; int n = j >> 10, k = j & 1023;
      wt_out[j] = (bf16_t)W_out[k * 512 + n];
    } else if (i < S1 + S2 + S3) {
      int j = i - S1 - S2; int n = j >> 9, k = j & 511;
      w1t[j] = (bf16_t)W1[k * 2048 + n];
    } else {
      int j = i - S1 - S2 - S3; int n = j >> 11, k = j & 2047;
      w2t[j] = (bf16_t)W2[k * 512 + n];
    }
  }
}

// ---------------- rmsnorm of masked input -> bf16 ----------------
__global__ __launch_bounds__(256) void rmsnorm_in_kernel(
    const float* __restrict__ x, const float* __restrict__ mask,
    bf16_t* __restrict__ u) {
  __shared__ float red[4];
  int row = blockIdx.x;
  float mk = mask[row];
  const float* xr = x + (size_t)row * 512;
  float v0 = xr[threadIdx.x] * mk;
  float v1 = xr[threadIdx.x + 256] * mk;
  float ss = block_sum256(v0 * v0 + v1 * v1, red);
  float r = rsqrtf(ss * (1.f / 512.f) + EPS);
  bf16_t* ur = u + (size_t)row * 512;
  ur[threadIdx.x] = (bf16_t)(v0 * r);
  ur[threadIdx.x + 256] = (bf16_t)(v1 * r);
}

// ---------------- rmsnorm of 2*m -> bf16 ----------------
__global__ __launch_bounds__(256) void rmsnorm2_kernel(
    const float* __restrict__ m, bf16_t* __restrict__ h) {
  __shared__ float red[4];
  int row = blockIdx.x;
  const float* mr = m + (size_t)row * 512;
  float v0 = 2.f * mr[threadIdx.x];
  float v1 = 2.f * mr[threadIdx.x + 256];
  float ss = block_sum256(v0 * v0 + v1 * v1, red);
  float r = rsqrtf(ss * (1.f / 512.f) + EPS);
  bf16_t* hr = h + (size_t)row * 512;
  hr[threadIdx.x] = (bf16_t)(v0 * r);
  hr[threadIdx.x + 256] = (bf16_t)(v1 * r);
}

// ---------------- MFMA GEMM: C[M,N] = A[M,K](bf16) @ Bt[N,K](bf16)^T ----------------
template <int EPI>
__global__ __launch_bounds__(256, 2) void gemm_kernel(
    const bf16_t* __restrict__ A, const bf16_t* __restrict__ Bt,
    int M, int N, int K,
    float* __restrict__ o0, float* __restrict__ o1, float* __restrict__ o2,
    bf16_t* __restrict__ ob, const float* __restrict__ bias,
    const float* __restrict__ extra) {
  __shared__ bf16_t As[128 * 32];
  __shared__ bf16_t Bs[128 * 32];
  const int tid = threadIdx.x;
  const int lane = tid & 63;
  const int w = tid >> 6;
  const int tileM = blockIdx.y * 128;
  const int tileN = blockIdx.x * 128;

  f32x4 acc[4][4] = {};

  const int wm = (w >> 1) * 64;
  const int wn = (w & 1) * 64;
  const int fr = lane & 15;
  const int fk = (lane >> 4) * 8;

  for (int k0 = 0; k0 < K; k0 += 32) {
    __syncthreads();
#pragma unroll
    for (int i = 0; i < 2; ++i) {
      int rloc = w * 32 + i * 16 + (lane >> 2);
      int cb = (lane & 3) * 16;   // byte offset within 64B row
      const char* ga = (const char*)(A + (size_t)(tileM + rloc) * K + k0) + cb;
      gl_lds16(ga, (void*)&As[(w * 32 + i * 16) * 32]);
      int rn = tileN + rloc;
      if (rn >= N) rn = N - 1;
      const char* gb = (const char*)(Bt + (size_t)rn * K + k0) + cb;
      gl_lds16(gb, (void*)&Bs[(w * 32 + i * 16) * 32]);
    }
    __syncthreads();

    bf16x8 av[4], bv[4];
#pragma unroll
    for (int i = 0; i < 4; ++i)
      av[i] = *(const bf16x8*)&As[(wm + i * 16 + fr) * 32 + fk];
#pragma unroll
    for (int j = 0; j < 4; ++j)
      bv[j] = *(const bf16x8*)&Bs[(wn + j * 16 + fr) * 32 + fk];
#pragma unroll
    for (int i = 0; i < 4; ++i)
#pragma unroll
      for (int j = 0; j < 4; ++j)
        acc[i][j] = __builtin_amdgcn_mfma_f32_16x16x32_bf16(av[i], bv[j], acc[i][j], 0, 0, 0);
  }

  const int cn = lane & 15;
  const int r0 = (lane >> 4) * 4;
#pragma unroll
  for (int i = 0; i < 4; ++i) {
#pragma unroll
    for (int j = 0; j < 4; ++j) {
      int gn = tileN + wn + j * 16 + cn;
      if (gn >= N) continue;
#pragma unroll
      for (int r = 0; r < 4; ++r) {
        int gm = tileM + wm + i * 16 + r0 + r;
        float v = acc[i][j][r];
        if (EPI == 0) {
          o0[(size_t)gm * N + gn] = v;
        } else if (EPI == 1) {
          if (gn < D_INNER) {
            o0[(size_t)gm * D_INNER + gn] = v;                       // z
          } else if (gn < D_INNER + CONV_DIM) {
            o1[(size_t)gm * CONV_DIM + (gn - D_INNER)] = v;          // xBC raw
          } else {
            int hh = gn - (D_INNER + CONV_DIM);
            o2[(size_t)gm * NHEADS + hh] = softplus_f(v + bias[hh]); // dt
          }
        } else if (EPI == 2) {
          ob[(size_t)gm * N + gn] = (bf16_t)gelu_tanh_f(v + bias[gn]);
        } else if (EPI == 3) {
          o0[(size_t)gm * N + gn] = v + bias[gn] + 2.f * extra[(size_t)gm * N + gn];
        }
      }
    }
  }
}

// ---------------- causal conv1d (k=4) + silu + mask ----------------
__global__ __launch_bounds__(384) void conv_silu_kernel(
    const float* __restrict__ xbc_raw, const float* __restrict__ conv_w,
    const float* __restrict__ conv_b, const float* __restrict__ mask,
    float* __restrict__ xbc_conv) {
  int row = blockIdx.x;
  int t = row & (L_SEQ - 1);
  float mk = mask[row];
#pragma unroll
  for (int k = 0; k < 3; ++k) {
    int c = threadIdx.x + k * 384;
    float4 wv = ((const float4*)conv_w)[c];   // conv_w[c][0..3]
    float acc = conv_b[c];
    if (t >= 3) acc += wv.x * xbc_raw[(size_t)(row - 3) * CONV_DIM + c];
    if (t >= 2) acc += wv.y * xbc_raw[(size_t)(row - 2) * CONV_DIM + c];
    if (t >= 1) acc += wv.z * xbc_raw[(size_t)(row - 1) * CONV_DIM + c];
    acc += wv.w * xbc_raw[(size_t)row * CONV_DIM + c];
    xbc_conv[(size_t)row * CONV_DIM + c] = silu_f(acc) * mk;
  }
}

// ================= SSD chunked scan =================
// Chunk size T=64. Per (dir,b,h,chunk):
//   la[i] = inclusive prefix of dt[i]*A  (i=0..63)
//   Gt = B @ C^T           (Gt[s,t] = sum_n B[s][n] C[t][n])
//   M[t][s] = Gt[s,t] * exp(la[t]-la[s]) * dt[s]  for s<=t else 0
//   Y_intra = M @ X        -> y2
//   Tc = X^T @ (w.B),  w[s] = exp(la[63]-la[s])*dt[s]   -> Tc_buf
//   la -> la_buf
// Then serial per (dir,b,h): S = exp(la63)*S + Tc;  Y_state = diag(exp(la)) C @ S^T, RMW into y2.

// ---------------- K1: per-chunk parallel kernel (8192 blocks) ----------------
__global__ __launch_bounds__(256) void scan_chunk_kernel(
    const float* __restrict__ xbc, const float* __restrict__ dt_all,
    const float* __restrict__ A_log,
    bf16_t* __restrict__ y2, bf16_t* __restrict__ Tc_buf,
    float* __restrict__ la_buf) {
  const int bid = blockIdx.x;
  const int c = bid & 31, h = (bid >> 5) & 15, b = (bid >> 9) & 7, dir = bid >> 12;
  const float A_h = -expf(A_log[h]);
  const int tid = threadIdx.x, w = tid >> 6, lane = tid & 63;
  const int fr = lane & 15, fk = (lane >> 4) * 8;

  __shared__ __align__(16) bf16_t sB[64][72];    // B rows [s][n]; aliased as M[t][s] later
  __shared__ __align__(16) bf16_t sC[64][72];    // C rows [t][n]
  __shared__ __align__(16) bf16_t sXt[64][72];   // X^T [p][s]
  __shared__ __align__(16) bf16_t sBwt[64][72];  // (w.B)^T [n][s]
  __shared__ float sLa[64], sDt[64], sW[64];

  const size_t base = (size_t)b * L_SEQ;
#define ROWOF(i) (base + (size_t)(dir ? (L_SEQ - 1 - (c * 64 + (i))) : (c * 64 + (i))))

  if (tid < 64) sDt[tid] = dt_all[ROWOF(tid) * NHEADS + h];

  float bB[16];
#pragma unroll
  for (int r = 0; r < 16; ++r) {
    int i = w * 16 + r;
    const float* src = xbc + ROWOF(i) * CONV_DIM;
    float xv = src[h * 64 + lane];
    float bv = src[D_INNER + lane];
    float cv = src[D_INNER + D_STATE + lane];
    bB[r] = bv;
    sB[i][lane] = (bf16_t)bv;
    sC[i][lane] = (bf16_t)cv;
    sXt[lane][i] = (bf16_t)xv;
  }
  __syncthreads();

  if (w == 0) {
    float v = sDt[lane] * A_h;
#pragma unroll
    for (int d = 1; d < 64; d <<= 1) {
      float o = __shfl_up(v, d, 64);
      if (lane >= d) v += o;
    }
    sLa[lane] = v;
    float la63 = __shfl(v, 63, 64);
    sW[lane] = __expf(la63 - v) * sDt[lane];
  }
  __syncthreads();

  // weighted-transposed B, and la out
#pragma unroll
  for (int r = 0; r < 16; ++r) {
    int i = w * 16 + r;
    sBwt[lane][i] = (bf16_t)(bB[r] * sW[i]);
  }
  if (tid < 64) la_buf[(size_t)bid * 64 + tid] = sLa[tid];

  // GEMM1: Gt[s, t-tile w] = B @ C^T (skip all-zero upper s-tiles: mi > w)
  f32x4 acc1[4] = {};
#pragma unroll
  for (int k0 = 0; k0 < 64; k0 += 32) {
    bf16x8 bv = *(const bf16x8*)&sC[w * 16 + fr][k0 + fk];
#pragma unroll
    for (int mi = 0; mi < 4; ++mi) {
      if (mi <= w) {
        bf16x8 av = *(const bf16x8*)&sB[mi * 16 + fr][k0 + fk];
        acc1[mi] = __builtin_amdgcn_mfma_f32_16x16x32_bf16(av, bv, acc1[mi], 0, 0, 0);
      }
    }
  }
  __syncthreads();   // GEMM1 reads done (sB can be overwritten); sBwt visible

  // build M[t][s] into sB alias
  {
    bf16_t (*sM)[72] = sB;
    float la_t = sLa[w * 16 + fr];
    int t = w * 16 + fr;
#pragma unroll
    for (int mi = 0; mi < 4; ++mi) {
#pragma unroll
      for (int r = 0; r < 4; ++r) {
        int s = mi * 16 + (lane >> 4) * 4 + r;
        float mv = 0.f;
        if (s <= t) mv = acc1[mi][r] * __expf(la_t - sLa[s]) * sDt[s];
        sM[t][s] = (bf16_t)mv;
      }
    }
  }

  // GEMM3: Tc[p, n-tile w] = X^T @ Bw  (independent of M writes)
  f32x4 acc3[4] = {};
#pragma unroll
  for (int k0 = 0; k0 < 64; k0 += 32) {
    bf16x8 bv = *(const bf16x8*)&sBwt[w * 16 + fr][k0 + fk];
#pragma unroll
    for (int mi = 0; mi < 4; ++mi) {
      bf16x8 av = *(const bf16x8*)&sXt[mi * 16 + fr][k0 + fk];
      acc3[mi] = __builtin_amdgcn_mfma_f32_16x16x32_bf16(av, bv, acc3[mi], 0, 0, 0);
    }
  }
  __syncthreads();   // M visible

  // GEMM2: Y[t, p-tile w] = M @ X
  f32x4 acc2[4] = {};
  {
    bf16_t (*sM)[72] = sB;
#pragma unroll
    for (int k0 = 0; k0 < 64; k0 += 32) {
      bf16x8 bv = *(const bf16x8*)&sXt[w * 16 + fr][k0 + fk];
#pragma unroll
      for (int mi = 0; mi < 4; ++mi) {
        bf16x8 av = *(const bf16x8*)&sM[mi * 16 + fr][k0 + fk];
        acc2[mi] = __builtin_amdgcn_mfma_f32_16x16x32_bf16(av, bv, acc2[mi], 0, 0, 0);
      }
    }
  }

  // stores
  bf16_t* yout = y2 + (size_t)dir * NROWS * D_INNER;
  bf16_t* tco = Tc_buf + (size_t)bid * 4096;
#pragma unroll
  for (int mi = 0; mi < 4; ++mi) {
#pragma unroll
    for (int r = 0; r < 4; ++r) {
      int rowl = mi * 16 + (lane >> 4) * 4 + r;
      int coll = w * 16 + fr;
      yout[ROWOF(rowl) * D_INNER + h * 64 + coll] = (bf16_t)acc2[mi][r];
      tco[rowl * 64 + coll] = (bf16_t)acc3[mi][r];
    }
  }
#undef ROWOF
}

// ---------------- K2: serial state scan + Y_state RMW (256 blocks) ----------------
__global__ __launch_bounds__(256) void scan_state_kernel(
    const float* __restrict__ xbc, const bf16_t* __restrict__ Tc_buf,
    const float* __restrict__ la_buf, bf16_t* __restrict__ y2) {
  const int bid = blockIdx.x;                 // dir*128 + b*16 + h
  const int h = bid & 15, b = (bid >> 4) & 7, dir = bid >> 7;
  const int tid = threadIdx.x, w = tid >> 6, lane = tid & 63;
  const int fr = lane & 15, fk = (lane >> 4) * 8;

  __shared__ __align__(16) bf16_t sS[64][72];   // S rows [p][n]
  __shared__ __align__(16) bf16_t sC[64][72];   // C rows [t][n]
  __shared__ float sLa[64];

  float S[16] = {};
  const int sp = tid >> 2, sn0 = (tid & 3) * 16;
  const size_t base = (size_t)b * L_SEQ;
  bf16_t* yout = y2 + (size_t)dir * NROWS * D_INNER;
  const bf16_t* tcb = Tc_buf + ((size_t)bid * 32) * 4096;
  const float* lab = la_buf + ((size_t)bid * 32) * 64;

  // prefetch chunk 0
  float laP = (tid < 64) ? lab[tid] : 0.f;
  float cP[16];
#pragma unroll
  for (int r = 0; r < 16; ++r) {
    int t = w * 16 + r;
    int tr = dir ? (L_SEQ - 1 - t) : t;
    cP[r] = xbc[(base + tr) * CONV_DIM + D_INNER + D_STATE + lane];
  }
  bf16x8 tcP0 = *(const bf16x8*)&tcb[sp * 64 + sn0];
  bf16x8 tcP1 = *(const bf16x8*)&tcb[sp * 64 + sn0 + 8];

  for (int cc = 0; cc < 32; ++cc) {
    // stage
    if (tid < 64) sLa[tid] = laP;
#pragma unroll
    for (int r = 0; r < 16; ++r) sC[w * 16 + r][lane] = (bf16_t)cP[r];
    {
      bf16_t tmp[16];
#pragma unroll
      for (int j = 0; j < 16; ++j) tmp[j] = (bf16_t)S[j];
      *(bf16x8*)&sS[sp][sn0] = *(bf16x8*)&tmp[0];
      *(bf16x8*)&sS[sp][sn0 + 8] = *(bf16x8*)&tmp[8];
    }
    __syncthreads();

    // prefetch next chunk (clamped) — overlaps GEMM below
    int cn = (cc < 31) ? cc + 1 : 31;
    float laN = (tid < 64) ? lab[(size_t)cn * 64 + tid] : 0.f;
    float cN[16];
#pragma unroll
    for (int r = 0; r < 16; ++r) {
      int t = cn * 64 + w * 16 + r;
      int tr = dir ? (L_SEQ - 1 - t) : t;
      cN[r] = xbc[(base + tr) * CONV_DIM + D_INNER + D_STATE + lane];
    }
    bf16x8 tcN0 = *(const bf16x8*)&tcb[(size_t)cn * 4096 + sp * 64 + sn0];
    bf16x8 tcN1 = *(const bf16x8*)&tcb[(size_t)cn * 4096 + sp * 64 + sn0 + 8];

    // GEMM: Ystate[t, p-tile w] = C @ S^T, then row-scale by exp(la[t])
    f32x4 acc[4] = {};
#pragma unroll
    for (int k0 = 0; k0 < 64; k0 += 32) {
      bf16x8 bv = *(const bf16x8*)&sS[w * 16 + fr][k0 + fk];
#pragma unroll
      for (int mi = 0; mi < 4; ++mi) {
        bf16x8 av = *(const bf16x8*)&sC[mi * 16 + fr][k0 + fk];
        acc[mi] = __builtin_amdgcn_mfma_f32_16x16x32_bf16(av, bv, acc[mi], 0, 0, 0);
      }
    }
    float dtot = __expf(sLa[63]);
    int p = w * 16 + fr;
#pragma unroll
    for (int mi = 0; mi < 4; ++mi) {
#pragma unroll
      for (int r = 0; r < 4; ++r) {
        int tl = mi * 16 + (lane >> 4) * 4 + r;
        float v = acc[mi][r] * __expf(sLa[tl]);
        int t = cc * 64 + tl;
        int tr = dir ? (L_SEQ - 1 - t) : t;
        size_t g = (base + tr) * D_INNER + h * 64 + p;
        yout[g] = (bf16_t)((float)yout[g] + v);
      }
    }
    // S update
    const bf16_t* t0 = (const bf16_t*)&tcP0;
    const bf16_t* t1 = (const bf16_t*)&tcP1;
#pragma unroll
    for (int j = 0; j < 8; ++j) S[j] = dtot * S[j] + (float)t0[j];
#pragma unroll
    for (int j = 0; j < 8; ++j) S[8 + j] = dtot * S[8 + j] + (float)t1[j];

    laP = laN; tcP0 = tcN0; tcP1 = tcN1;
#pragma unroll
    for (int r = 0; r < 16; ++r) cP[r] = cN[r];
    __syncthreads();
  }
}

// ---------------- combine: y = rmsnorm((yf+yb+D*xs) * silu(z)) * norm_w -> bf16 ----------------
__global__ __launch_bounds__(256) void combine_kernel(
    const bf16_t* __restrict__ y2, const float* __restrict__ xbc_conv,
    const float* __restrict__ z, const float* __restrict__ Dp,
    const float* __restrict__ norm_w, bf16_t* __restrict__ yn) {
  __shared__ float red[4];
  int row = blockIdx.x;
  const bf16_t* yf = y2 + (size_t)row * D_INNER;
  const bf16_t* yb = y2 + (size_t)NROWS * D_INNER + (size_t)row * D_INNER;
  const float* xs = xbc_conv + (size_t)row * CONV_DIM;
  const float* zr = z + (size_t)row * D_INNER;

  float g[4];
  float ss = 0.f;
#pragma unroll
  for (int k = 0; k < 4; ++k) {
    int c = threadIdx.x + k * 256;
    float v = (float)yf[c] + (float)yb[c] + Dp[c >> 6] * xs[c];
    float gg = v * silu_f(zr[c]);
    g[k] = gg;
    ss += gg * gg;
  }
  ss = block_sum256(ss, red);
  float r = rsqrtf(ss * (1.f / 1024.f) + EPS);
  bf16_t* yr = yn + (size_t)row * D_INNER;
#pragma unroll
  for (int k = 0; k < 4; ++k) {
    int c = threadIdx.x + k * 256;
    yr[c] = (bf16_t)(g[k] * r * norm_w[c]);
  }
}

// ---------------- launcher ----------------
extern "C" void kernel_launch(void* const* d_in, const int* in_sizes, int n_in,
                              void* d_out, int out_size, void* d_ws, size_t ws_size,
                              hipStream_t stream) {
  const float* x       = (const float*)d_in[0];
  const float* mask    = (const float*)d_in[1];
  const float* W_in    = (const float*)d_in[2];
  const float* conv_w  = (const float*)d_in[3];
  const float* conv_b  = (const float*)d_in[4];
  const float* dt_bias = (const float*)d_in[5];
  const float* A_log   = (const float*)d_in[6];
  const float* Dp      = (const float*)d_in[7];
  const float* norm_w  = (const float*)d_in[8];
  const float* W_out   = (const float*)d_in[9];
  const float* W1      = (const float*)d_in[10];
  const float* b1      = (const float*)d_in[11];
  const float* W2      = (const float*)d_in[12];
  const float* b2      = (const float*)d_in[13];

  float* out_x  = (float*)d_out;                       // 16384*512
  float* out_m  = out_x + (size_t)NROWS * 512;         // 16384*512
  float* out_dt = out_m + (size_t)NROWS * 512;         // 16384*16
  float* out_z  = out_dt + (size_t)NROWS * NHEADS;     // 16384*1024

  char* ws = (char*)d_ws;
  bf16_t* wt_in    = (bf16_t*)(ws + OFF_WT_IN);
  bf16_t* wt_out   = (bf16_t*)(ws + OFF_WT_OUT);
  bf16_t* w1t      = (bf16_t*)(ws + OFF_W1T);
  bf16_t* w2t      = (bf16_t*)(ws + OFF_W2T);
  bf16_t* u_bf     = (bf16_t*)(ws + OFF_U);            // reused: la_buf (scan), h_bf (ffn)
  float*  xbc_raw  = (float*)(ws + OFF_XBC_RAW);       // reused: Tc_buf (scan), gelu bf16 (ffn)
  float*  xbc_conv = (float*)(ws + OFF_XBC_CONV);
  bf16_t* y2       = (bf16_t*)(ws + OFF_Y2);
  bf16_t* yn       = (bf16_t*)(ws + OFF_YN);
  bf16_t* h_bf     = u_bf;
  bf16_t* gelu_bf  = (bf16_t*)(ws + OFF_XBC_RAW);
  bf16_t* Tc_buf   = (bf16_t*)(ws + OFF_XBC_RAW);      // 8192*4096 bf16 = 67 MB <= 75 MB region
  float*  la_buf   = (float*)(ws + OFF_U);             // 8192*64 f32 = 2 MB <= 16.7 MB region

  // 1. weights -> bf16 transposed
  prep_weights_kernel<<<14624, 256, 0, stream>>>(W_in, W_out, W1, W2, wt_in, wt_out, w1t, w2t);
  // 2. u = rmsnorm(x*mask)
  rmsnorm_in_kernel<<<NROWS, 256, 0, stream>>>(x, mask, u_bf);
  // 3. zxbcdt = u @ W_in, split into z / xBC / dt(softplus)
  gemm_kernel<1><<<dim3(18, 128), 256, 0, stream>>>(u_bf, wt_in, NROWS, D_IN_PROJ, 512,
                                                    out_z, xbc_raw, out_dt, nullptr, dt_bias, nullptr);
  // 4. conv1d + silu + mask
  conv_silu_kernel<<<NROWS, 384, 0, stream>>>(xbc_raw, conv_w, conv_b, mask, xbc_conv);
  // 5a. SSD chunked scan: per-chunk GEMMs (Y_intra, Tc, la)
  scan_chunk_kernel<<<8192, 256, 0, stream>>>(xbc_conv, out_dt, A_log, y2, Tc_buf, la_buf);
  // 5b. serial state pass + Y_state RMW
  scan_state_kernel<<<256, 256, 0, stream>>>(xbc_conv, Tc_buf, la_buf, y2);
  // 6. combine + gated rmsnorm
  combine_kernel<<<NROWS, 256, 0, stream>>>(y2, xbc_conv, out_z, Dp, norm_w, yn);
  // 7. m = yn @ W_out
  gemm_kernel<0><<<dim3(4, 128), 256, 0, stream>>>(yn, wt_out, NROWS, 512, 1024,
                                                   out_m, nullptr, nullptr, nullptr, nullptr, nullptr);
  // 8. h = rmsnorm(2m)
  rmsnorm2_kernel<<<NROWS, 256, 0, stream>>>(out_m, h_bf);
  // 9. g = gelu(h @ W1 + b1)
  gemm_kernel<2><<<dim3(16, 128), 256, 0, stream>>>(h_bf, w1t, NROWS, D_FF, 512,
                                                    nullptr, nullptr, nullptr, gelu_bf, b1, nullptr);
  // 10. x = 2m + g @ W2 + b2
  gemm_kernel<3><<<dim3(4, 128), 256, 0, stream>>>(gelu_bf, w2t, NROWS, 512, D_FF,
                                                   out_x, nullptr, nullptr, nullptr, b2, out_m);
}

// Round 4
// 725.877 us; speedup vs baseline: 2.1692x; 1.1164x over previous
//
#include <hip/hip_runtime.h>
#include <cstdint>
#include <cstddef>

// ---------------- constants ----------------
#define L_SEQ   2048
#define NROWS   16384            // B*L = 8*2048
#define D_MODEL 512
#define D_INNER 1024
#define D_STATE 64
#define NHEADS  16
#define CONV_DIM 1152
#define D_IN_PROJ 2192
#define D_FF 2048
#define EPS 1e-6f

typedef __bf16 bf16_t;
typedef __bf16 bf16x8 __attribute__((ext_vector_type(8)));
typedef float  f32x4  __attribute__((ext_vector_type(4)));

// workspace layout (bytes)
#define OFF_WT_IN    0ull                       // 2192*512 bf16  = 2,244,608
#define OFF_WT_OUT   2244608ull                 // 512*1024 bf16  = 1,048,576
#define OFF_W1T      3293184ull                 // 2048*512 bf16  = 2,097,152
#define OFF_W2T      5390336ull                 // 512*2048 bf16  = 2,097,152
#define OFF_U        7487488ull                 // 16384*512 bf16 (u_bf; reused: la_buf during scan, h_bf later)
#define OFF_XBC_RAW  24264704ull                // 16384*1152 f32 (xbc_raw; reused: Tc/S_buf during scan, gelu bf16 later)
#define OFF_XBC_CONV 99762176ull                // 16384*1152 f32
#define OFF_Y2       175259648ull               // 2*16384*1024 bf16 = 67,108,864
#define OFF_YN       242368512ull               // 16384*1024 bf16 = 33,554,432
// total ~276 MB

// ---------------- helpers ----------------
__device__ __forceinline__ void gl_lds16(const void* g, void* s) {
  __builtin_amdgcn_global_load_lds(
      (__attribute__((address_space(1))) void*)(void*)g,
      (__attribute__((address_space(3))) void*)s, 16, 0, 0);
}

__device__ __forceinline__ float block_sum256(float v, float* red) {
#pragma unroll
  for (int o = 32; o > 0; o >>= 1) v += __shfl_xor(v, o, 64);
  int w = threadIdx.x >> 6;
  if ((threadIdx.x & 63) == 0) red[w] = v;
  __syncthreads();
  return red[0] + red[1] + red[2] + red[3];
}

__device__ __forceinline__ float softplus_f(float x) {
  return (x > 20.f) ? x : log1pf(expf(x));
}
__device__ __forceinline__ float silu_f(float x) {
  return x / (1.f + expf(-x));
}
__device__ __forceinline__ float gelu_tanh_f(float x) {
  float x3 = x * x * x;
  return 0.5f * x * (1.f + tanhf(0.7978845608f * (x + 0.044715f * x3)));
}

// ---------------- weight prep: fp32 -> bf16, transposed ----------------
__global__ __launch_bounds__(256) void prep_weights_kernel(
    const float* __restrict__ W_in, const float* __restrict__ W_out,
    const float* __restrict__ W1, const float* __restrict__ W2,
    bf16_t* __restrict__ wt_in, bf16_t* __restrict__ wt_out,
    bf16_t* __restrict__ w1t, bf16_t* __restrict__ w2t) {
  const int S1 = D_IN_PROJ * 512;   // 1122304
  const int S2 = 512 * 1024;        // 524288
  const int S3 = 2048 * 512;        // 1048576
  const int S4 = 512 * 2048;        // 1048576
  const int total = S1 + S2 + S3 + S4;
  for (int i = blockIdx.x * 256 + threadIdx.x; i < total; i += gridDim.x * 256) {
    if (i < S1) {
      int n = i / 512, k = i - n * 512;
      wt_in[i] = (bf16_t)W_in[k * D_IN_PROJ + n];
    } else if (i < S1 + S2) {
      int j = i - S1; int n = j >> 10, k = j & 1023;
      wt_out[j] = (bf16_t)W_out[k * 512 + n];
    } else if (i < S1 + S2 + S3) {
      int j = i - S1 - S2; int n = j >> 9, k = j & 511;
      w1t[j] = (bf16_t)W1[k * 2048 + n];
    } else {
      int j = i - S1 - S2 - S3; int n = j >> 11, k = j & 2047;
      w2t[j] = (bf16_t)W2[k * 512 + n];
    }
  }
}

// ---------------- rmsnorm of masked input -> bf16 ----------------
__global__ __launch_bounds__(256) void rmsnorm_in_kernel(
    const float* __restrict__ x, const float* __restrict__ mask,
    bf16_t* __restrict__ u) {
  __shared__ float red[4];
  int row = blockIdx.x;
  float mk = mask[row];
  const float* xr = x + (size_t)row * 512;
  float v0 = xr[threadIdx.x] * mk;
  float v1 = xr[threadIdx.x + 256] * mk;
  float ss = block_sum256(v0 * v0 + v1 * v1, red);
  float r = rsqrtf(ss * (1.f / 512.f) + EPS);
  bf16_t* ur = u + (size_t)row * 512;
  ur[threadIdx.x] = (bf16_t)(v0 * r);
  ur[threadIdx.x + 256] = (bf16_t)(v1 * r);
}

// ---------------- rmsnorm of 2*m -> bf16 ----------------
__global__ __launch_bounds__(256) void rmsnorm2_kernel(
    const float* __restrict__ m, bf16_t* __restrict__ h) {
  __shared__ float red[4];
  int row = blockIdx.x;
  const float* mr = m + (size_t)row * 512;
  float v0 = 2.f * mr[threadIdx.x];
  float v1 = 2.f * mr[threadIdx.x + 256];
  float ss = block_sum256(v0 * v0 + v1 * v1, red);
  float r = rsqrtf(ss * (1.f / 512.f) + EPS);
  bf16_t* hr = h + (size_t)row * 512;
  hr[threadIdx.x] = (bf16_t)(v0 * r);
  hr[threadIdx.x + 256] = (bf16_t)(v1 * r);
}

// ---------------- MFMA GEMM: C[M,N] = A[M,K](bf16) @ Bt[N,K](bf16)^T ----------------
template <int EPI>
__global__ __launch_bounds__(256, 2) void gemm_kernel(
    const bf16_t* __restrict__ A, const bf16_t* __restrict__ Bt,
    int M, int N, int K,
    float* __restrict__ o0, float* __restrict__ o1, float* __restrict__ o2,
    bf16_t* __restrict__ ob, const float* __restrict__ bias,
    const float* __restrict__ extra) {
  __shared__ bf16_t As[128 * 32];
  __shared__ bf16_t Bs[128 * 32];
  const int tid = threadIdx.x;
  const int lane = tid & 63;
  const int w = tid >> 6;
  const int tileM = blockIdx.y * 128;
  const int tileN = blockIdx.x * 128;

  f32x4 acc[4][4] = {};

  const int wm = (w >> 1) * 64;
  const int wn = (w & 1) * 64;
  const int fr = lane & 15;
  const int fk = (lane >> 4) * 8;

  for (int k0 = 0; k0 < K; k0 += 32) {
    __syncthreads();
#pragma unroll
    for (int i = 0; i < 2; ++i) {
      int rloc = w * 32 + i * 16 + (lane >> 2);
      int cb = (lane & 3) * 16;   // byte offset within 64B row
      const char* ga = (const char*)(A + (size_t)(tileM + rloc) * K + k0) + cb;
      gl_lds16(ga, (void*)&As[(w * 32 + i * 16) * 32]);
      int rn = tileN + rloc;
      if (rn >= N) rn = N - 1;
      const char* gb = (const char*)(Bt + (size_t)rn * K + k0) + cb;
      gl_lds16(gb, (void*)&Bs[(w * 32 + i * 16) * 32]);
    }
    __syncthreads();

    bf16x8 av[4], bv[4];
#pragma unroll
    for (int i = 0; i < 4; ++i)
      av[i] = *(const bf16x8*)&As[(wm + i * 16 + fr) * 32 + fk];
#pragma unroll
    for (int j = 0; j < 4; ++j)
      bv[j] = *(const bf16x8*)&Bs[(wn + j * 16 + fr) * 32 + fk];
#pragma unroll
    for (int i = 0; i < 4; ++i)
#pragma unroll
      for (int j = 0; j < 4; ++j)
        acc[i][j] = __builtin_amdgcn_mfma_f32_16x16x32_bf16(av[i], bv[j], acc[i][j], 0, 0, 0);
  }

  const int cn = lane & 15;
  const int r0 = (lane >> 4) * 4;
#pragma unroll
  for (int i = 0; i < 4; ++i) {
#pragma unroll
    for (int j = 0; j < 4; ++j) {
      int gn = tileN + wn + j * 16 + cn;
      if (gn >= N) continue;
#pragma unroll
      for (int r = 0; r < 4; ++r) {
        int gm = tileM + wm + i * 16 + r0 + r;
        float v = acc[i][j][r];
        if (EPI == 0) {
          o0[(size_t)gm * N + gn] = v;
        } else if (EPI == 1) {
          if (gn < D_INNER) {
            o0[(size_t)gm * D_INNER + gn] = v;                       // z
          } else if (gn < D_INNER + CONV_DIM) {
            o1[(size_t)gm * CONV_DIM + (gn - D_INNER)] = v;          // xBC raw
          } else {
            int hh = gn - (D_INNER + CONV_DIM);
            o2[(size_t)gm * NHEADS + hh] = softplus_f(v + bias[hh]); // dt
          }
        } else if (EPI == 2) {
          ob[(size_t)gm * N + gn] = (bf16_t)gelu_tanh_f(v + bias[gn]);
        } else if (EPI == 3) {
          o0[(size_t)gm * N + gn] = v + bias[gn] + 2.f * extra[(size_t)gm * N + gn];
        }
      }
    }
  }
}

// ---------------- causal conv1d (k=4) + silu + mask ----------------
__global__ __launch_bounds__(384) void conv_silu_kernel(
    const float* __restrict__ xbc_raw, const float* __restrict__ conv_w,
    const float* __restrict__ conv_b, const float* __restrict__ mask,
    float* __restrict__ xbc_conv) {
  int row = blockIdx.x;
  int t = row & (L_SEQ - 1);
  float mk = mask[row];
#pragma unroll
  for (int k = 0; k < 3; ++k) {
    int c = threadIdx.x + k * 384;
    float4 wv = ((const float4*)conv_w)[c];   // conv_w[c][0..3]
    float acc = conv_b[c];
    if (t >= 3) acc += wv.x * xbc_raw[(size_t)(row - 3) * CONV_DIM + c];
    if (t >= 2) acc += wv.y * xbc_raw[(size_t)(row - 2) * CONV_DIM + c];
    if (t >= 1) acc += wv.z * xbc_raw[(size_t)(row - 1) * CONV_DIM + c];
    acc += wv.w * xbc_raw[(size_t)row * CONV_DIM + c];
    xbc_conv[(size_t)row * CONV_DIM + c] = silu_f(acc) * mk;
  }
}

// ================= SSD chunked scan =================
// Chunk T=64. K1 (parallel, 8192 blocks): la prefix, Gt=B@C^T, M-mask, Y_intra=M@X -> y2,
//   Tc = X^T@(w.B) -> Tc_buf, la -> la_buf.
// K2a (parallel over state elems): in-place over Tc_buf, replace Tc_c with S_c
//   (state ENTERING chunk c): S=0; for c: {store S; S = exp(la63_c)*S + Tc_c}.
// K2b (parallel, 8192 blocks): Y_state[t,p] = exp(la[t]) * sum_n C[t,n]*S_c[p,n], RMW y2.

// ---------------- K1: per-chunk parallel kernel (8192 blocks) ----------------
__global__ __launch_bounds__(256) void scan_chunk_kernel(
    const float* __restrict__ xbc, const float* __restrict__ dt_all,
    const float* __restrict__ A_log,
    bf16_t* __restrict__ y2, bf16_t* __restrict__ Tc_buf,
    float* __restrict__ la_buf) {
  const int bid = blockIdx.x;
  const int c = bid & 31, h = (bid >> 5) & 15, b = (bid >> 9) & 7, dir = bid >> 12;
  const float A_h = -expf(A_log[h]);
  const int tid = threadIdx.x, w = tid >> 6, lane = tid & 63;
  const int fr = lane & 15, fk = (lane >> 4) * 8;

  __shared__ __align__(16) bf16_t sB[64][72];    // B rows [s][n]; aliased as M[t][s] later
  __shared__ __align__(16) bf16_t sC[64][72];    // C rows [t][n]
  __shared__ __align__(16) bf16_t sXt[64][72];   // X^T [p][s]
  __shared__ __align__(16) bf16_t sBwt[64][72];  // (w.B)^T [n][s]
  __shared__ float sLa[64], sDt[64], sW[64];

  const size_t base = (size_t)b * L_SEQ;
#define ROWOF(i) (base + (size_t)(dir ? (L_SEQ - 1 - (c * 64 + (i))) : (c * 64 + (i))))

  if (tid < 64) sDt[tid] = dt_all[ROWOF(tid) * NHEADS + h];

  float bB[16];
#pragma unroll
  for (int r = 0; r < 16; ++r) {
    int i = w * 16 + r;
    const float* src = xbc + ROWOF(i) * CONV_DIM;
    float xv = src[h * 64 + lane];
    float bv = src[D_INNER + lane];
    float cv = src[D_INNER + D_STATE + lane];
    bB[r] = bv;
    sB[i][lane] = (bf16_t)bv;
    sC[i][lane] = (bf16_t)cv;
    sXt[lane][i] = (bf16_t)xv;
  }
  __syncthreads();

  if (w == 0) {
    float v = sDt[lane] * A_h;
#pragma unroll
    for (int d = 1; d < 64; d <<= 1) {
      float o = __shfl_up(v, d, 64);
      if (lane >= d) v += o;
    }
    sLa[lane] = v;
    float la63 = __shfl(v, 63, 64);
    sW[lane] = __expf(la63 - v) * sDt[lane];
  }
  __syncthreads();

  // weighted-transposed B, and la out
#pragma unroll
  for (int r = 0; r < 16; ++r) {
    int i = w * 16 + r;
    sBwt[lane][i] = (bf16_t)(bB[r] * sW[i]);
  }
  if (tid < 64) la_buf[(size_t)bid * 64 + tid] = sLa[tid];

  // GEMM1: Gt[s, t-tile w] = B @ C^T (skip all-zero upper s-tiles: mi > w)
  f32x4 acc1[4] = {};
#pragma unroll
  for (int k0 = 0; k0 < 64; k0 += 32) {
    bf16x8 bv = *(const bf16x8*)&sC[w * 16 + fr][k0 + fk];
#pragma unroll
    for (int mi = 0; mi < 4; ++mi) {
      if (mi <= w) {
        bf16x8 av = *(const bf16x8*)&sB[mi * 16 + fr][k0 + fk];
        acc1[mi] = __builtin_amdgcn_mfma_f32_16x16x32_bf16(av, bv, acc1[mi], 0, 0, 0);
      }
    }
  }
  __syncthreads();   // GEMM1 reads done (sB can be overwritten); sBwt visible

  // build M[t][s] into sB alias
  {
    bf16_t (*sM)[72] = sB;
    float la_t = sLa[w * 16 + fr];
    int t = w * 16 + fr;
#pragma unroll
    for (int mi = 0; mi < 4; ++mi) {
#pragma unroll
      for (int r = 0; r < 4; ++r) {
        int s = mi * 16 + (lane >> 4) * 4 + r;
        float mv = 0.f;
        if (s <= t) mv = acc1[mi][r] * __expf(la_t - sLa[s]) * sDt[s];
        sM[t][s] = (bf16_t)mv;
      }
    }
  }

  // GEMM3: Tc[p, n-tile w] = X^T @ Bw  (independent of M writes)
  f32x4 acc3[4] = {};
#pragma unroll
  for (int k0 = 0; k0 < 64; k0 += 32) {
    bf16x8 bv = *(const bf16x8*)&sBwt[w * 16 + fr][k0 + fk];
#pragma unroll
    for (int mi = 0; mi < 4; ++mi) {
      bf16x8 av = *(const bf16x8*)&sXt[mi * 16 + fr][k0 + fk];
      acc3[mi] = __builtin_amdgcn_mfma_f32_16x16x32_bf16(av, bv, acc3[mi], 0, 0, 0);
    }
  }
  __syncthreads();   // M visible

  // GEMM2: Y[t, p-tile w] = M @ X
  f32x4 acc2[4] = {};
  {
    bf16_t (*sM)[72] = sB;
#pragma unroll
    for (int k0 = 0; k0 < 64; k0 += 32) {
      bf16x8 bv = *(const bf16x8*)&sXt[w * 16 + fr][k0 + fk];
#pragma unroll
      for (int mi = 0; mi < 4; ++mi) {
        bf16x8 av = *(const bf16x8*)&sM[mi * 16 + fr][k0 + fk];
        acc2[mi] = __builtin_amdgcn_mfma_f32_16x16x32_bf16(av, bv, acc2[mi], 0, 0, 0);
      }
    }
  }

  // stores
  bf16_t* yout = y2 + (size_t)dir * NROWS * D_INNER;
  bf16_t* tco = Tc_buf + (size_t)bid * 4096;
#pragma unroll
  for (int mi = 0; mi < 4; ++mi) {
#pragma unroll
    for (int r = 0; r < 4; ++r) {
      int rowl = mi * 16 + (lane >> 4) * 4 + r;
      int coll = w * 16 + fr;
      yout[ROWOF(rowl) * D_INNER + h * 64 + coll] = (bf16_t)acc2[mi][r];
      tco[rowl * 64 + coll] = (bf16_t)acc3[mi][r];
    }
  }
#undef ROWOF
}

// ---------------- K2a: parallel state prefix, in-place Tc -> S ----------------
// grid = 512: g = bid>>1 (dir*128+b*16+h), part = bid&1. 256 thr x 8 elems.
__global__ __launch_bounds__(256) void state_prefix_kernel(
    const float* __restrict__ la_buf, bf16_t* __restrict__ Tc_buf) {
  const int g = blockIdx.x >> 1;
  const int e0 = (blockIdx.x & 1) * 2048 + threadIdx.x * 8;
  bf16_t* tc = Tc_buf + (size_t)g * 32 * 4096 + e0;
  const float* la63 = la_buf + (size_t)g * 32 * 64 + 63;
  float S[8] = {};
  for (int cc = 0; cc < 32; ++cc) {
    bf16x8 t = *(const bf16x8*)(tc + (size_t)cc * 4096);
    float d = __expf(la63[cc * 64]);
    bf16_t sb[8];
#pragma unroll
    for (int j = 0; j < 8; ++j) sb[j] = (bf16_t)S[j];
    *(bf16x8*)(tc + (size_t)cc * 4096) = *(bf16x8*)sb;
    const bf16_t* tp = (const bf16_t*)&t;
#pragma unroll
    for (int j = 0; j < 8; ++j) S[j] = d * S[j] + (float)tp[j];
  }
}

// ---------------- K2b: Y_state apply (8192 blocks, fully parallel) ----------------
__global__ __launch_bounds__(256) void ystate_kernel(
    const float* __restrict__ xbc, const bf16_t* __restrict__ S_buf,
    const float* __restrict__ la_buf, bf16_t* __restrict__ y2) {
  const int bid = blockIdx.x;
  const int c = bid & 31, h = (bid >> 5) & 15, b = (bid >> 9) & 7, dir = bid >> 12;
  const int tid = threadIdx.x, w = tid >> 6, lane = tid & 63;
  const int fr = lane & 15, fk = (lane >> 4) * 8;
  const size_t base = (size_t)b * L_SEQ;

  const bf16_t* Sp = S_buf + (size_t)bid * 4096;
  f32x4 acc[4] = {};
#pragma unroll
  for (int k0 = 0; k0 < 64; k0 += 32) {
    bf16x8 bv = *(const bf16x8*)&Sp[(w * 16 + fr) * 64 + k0 + fk];
#pragma unroll
    for (int mi = 0; mi < 4; ++mi) {
      int t = c * 64 + mi * 16 + fr;
      int tr = dir ? (L_SEQ - 1 - t) : t;
      const float* cp = xbc + (base + tr) * CONV_DIM + D_INNER + D_STATE + k0 + fk;
      bf16_t av[8];
#pragma unroll
      for (int j = 0; j < 8; ++j) av[j] = (bf16_t)cp[j];
      acc[mi] = __builtin_amdgcn_mfma_f32_16x16x32_bf16(*(bf16x8*)av, bv, acc[mi], 0, 0, 0);
    }
  }
  const float* la = la_buf + (size_t)bid * 64;
  bf16_t* yout = y2 + (size_t)dir * NROWS * D_INNER;
  const int p = w * 16 + fr;
#pragma unroll
  for (int mi = 0; mi < 4; ++mi) {
#pragma unroll
    for (int r = 0; r < 4; ++r) {
      int tl = mi * 16 + (lane >> 4) * 4 + r;
      int t = c * 64 + tl;
      int tr = dir ? (L_SEQ - 1 - t) : t;
      size_t g = (base + tr) * D_INNER + h * 64 + p;
      float v = acc[mi][r] * __expf(la[tl]);
      yout[g] = (bf16_t)((float)yout[g] + v);
    }
  }
}

// ---------------- combine: y = rmsnorm((yf+yb+D*xs) * silu(z)) * norm_w -> bf16 ----------------
__global__ __launch_bounds__(256) void combine_kernel(
    const bf16_t* __restrict__ y2, const float* __restrict__ xbc_conv,
    const float* __restrict__ z, const float* __restrict__ Dp,
    const float* __restrict__ norm_w, bf16_t* __restrict__ yn) {
  __shared__ float red[4];
  int row = blockIdx.x;
  const bf16_t* yf = y2 + (size_t)row * D_INNER;
  const bf16_t* yb = y2 + (size_t)NROWS * D_INNER + (size_t)row * D_INNER;
  const float* xs = xbc_conv + (size_t)row * CONV_DIM;
  const float* zr = z + (size_t)row * D_INNER;

  float g[4];
  float ss = 0.f;
#pragma unroll
  for (int k = 0; k < 4; ++k) {
    int c = threadIdx.x + k * 256;
    float v = (float)yf[c] + (float)yb[c] + Dp[c >> 6] * xs[c];
    float gg = v * silu_f(zr[c]);
    g[k] = gg;
    ss += gg * gg;
  }
  ss = block_sum256(ss, red);
  float r = rsqrtf(ss * (1.f / 1024.f) + EPS);
  bf16_t* yr = yn + (size_t)row * D_INNER;
#pragma unroll
  for (int k = 0; k < 4; ++k) {
    int c = threadIdx.x + k * 256;
    yr[c] = (bf16_t)(g[k] * r * norm_w[c]);
  }
}

// ---------------- launcher ----------------
extern "C" void kernel_launch(void* const* d_in, const int* in_sizes, int n_in,
                              void* d_out, int out_size, void* d_ws, size_t ws_size,
                              hipStream_t stream) {
  const float* x       = (const float*)d_in[0];
  const float* mask    = (const float*)d_in[1];
  const float* W_in    = (const float*)d_in[2];
  const float* conv_w  = (const float*)d_in[3];
  const float* conv_b  = (const float*)d_in[4];
  const float* dt_bias = (const float*)d_in[5];
  const float* A_log   = (const float*)d_in[6];
  const float* Dp      = (const float*)d_in[7];
  const float* norm_w  = (const float*)d_in[8];
  const float* W_out   = (const float*)d_in[9];
  const float* W1      = (const float*)d_in[10];
  const float* b1      = (const float*)d_in[11];
  const float* W2      = (const float*)d_in[12];
  const float* b2      = (const float*)d_in[13];

  float* out_x  = (float*)d_out;                       // 16384*512
  float* out_m  = out_x + (size_t)NROWS * 512;         // 16384*512
  float* out_dt = out_m + (size_t)NROWS * 512;         // 16384*16
  float* out_z  = out_dt + (size_t)NROWS * NHEADS;     // 16384*1024

  char* ws = (char*)d_ws;
  bf16_t* wt_in    = (bf16_t*)(ws + OFF_WT_IN);
  bf16_t* wt_out   = (bf16_t*)(ws + OFF_WT_OUT);
  bf16_t* w1t      = (bf16_t*)(ws + OFF_W1T);
  bf16_t* w2t      = (bf16_t*)(ws + OFF_W2T);
  bf16_t* u_bf     = (bf16_t*)(ws + OFF_U);            // reused: la_buf (scan), h_bf (ffn)
  float*  xbc_raw  = (float*)(ws + OFF_XBC_RAW);       // reused: Tc/S_buf (scan), gelu bf16 (ffn)
  float*  xbc_conv = (float*)(ws + OFF_XBC_CONV);
  bf16_t* y2       = (bf16_t*)(ws + OFF_Y2);
  bf16_t* yn       = (bf16_t*)(ws + OFF_YN);
  bf16_t* h_bf     = u_bf;
  bf16_t* gelu_bf  = (bf16_t*)(ws + OFF_XBC_RAW);
  bf16_t* Tc_buf   = (bf16_t*)(ws + OFF_XBC_RAW);      // 8192*4096 bf16 = 67 MB <= 75 MB region
  float*  la_buf   = (float*)(ws + OFF_U);             // 8192*64 f32 = 2 MB <= 16.7 MB region

  // 1. weights -> bf16 transposed
  prep_weights_kernel<<<14624, 256, 0, stream>>>(W_in, W_out, W1, W2, wt_in, wt_out, w1t, w2t);
  // 2. u = rmsnorm(x*mask)
  rmsnorm_in_kernel<<<NROWS, 256, 0, stream>>>(x, mask, u_bf);
  // 3. zxbcdt = u @ W_in, split into z / xBC / dt(softplus)
  gemm_kernel<1><<<dim3(18, 128), 256, 0, stream>>>(u_bf, wt_in, NROWS, D_IN_PROJ, 512,
                                                    out_z, xbc_raw, out_dt, nullptr, dt_bias, nullptr);
  // 4. conv1d + silu + mask
  conv_silu_kernel<<<NROWS, 384, 0, stream>>>(xbc_raw, conv_w, conv_b, mask, xbc_conv);
  // 5a. SSD chunked scan: per-chunk GEMMs (Y_intra, Tc, la)
  scan_chunk_kernel<<<8192, 256, 0, stream>>>(xbc_conv, out_dt, A_log, y2, Tc_buf, la_buf);
  // 5b. parallel state prefix (in-place Tc -> S)
  state_prefix_kernel<<<512, 256, 0, stream>>>(la_buf, Tc_buf);
  // 5c. Y_state apply (fully parallel MFMA + RMW)
  ystate_kernel<<<8192, 256, 0, stream>>>(xbc_conv, Tc_buf, la_buf, y2);
  // 6. combine + gated rmsnorm
  combine_kernel<<<NROWS, 256, 0, stream>>>(y2, xbc_conv, out_z, Dp, norm_w, yn);
  // 7. m = yn @ W_out
  gemm_kernel<0><<<dim3(4, 128), 256, 0, stream>>>(yn, wt_out, NROWS, 512, 1024,
                                                   out_m, nullptr, nullptr, nullptr, nullptr, nullptr);
  // 8. h = rmsnorm(2m)
  rmsnorm2_kernel<<<NROWS, 256, 0, stream>>>(out_m, h_bf);
  // 9. g = gelu(h @ W1 + b1)
  gemm_kernel<2><<<dim3(16, 128), 256, 0, stream>>>(h_bf, w1t, NROWS, D_FF, 512,
                                                    nullptr, nullptr, nullptr, gelu_bf, b1, nullptr);
  // 10. x = 2m + g @ W2 + b2
  gemm_kernel<3><<<dim3(4, 128), 256, 0, stream>>>(gelu_bf, w2t, NROWS, 512, D_FF,
                                                   out_x, nullptr, nullptr, nullptr, b2, out_m);
}